// Round 8
// baseline (704.347 us; speedup 1.0000x reference)
//
#include <hip/hip_runtime.h>
#include <cstdint>
#include <cstddef>

#define NN 100000
#define NE 1600000
#define NBB 391   // dst buckets of 256 nodes: ceil(100000/256)

typedef short short8 __attribute__((ext_vector_type(8)));
typedef float floatx4 __attribute__((ext_vector_type(4)));
typedef uint32_t uintx4 __attribute__((ext_vector_type(4)));
typedef uint32_t uintx2 __attribute__((ext_vector_type(2)));

// ============ intermediate format: split-bf16 plane rows =============
// Every intermediate feature row of D channels is stored as 2D shorts:
//   [ hi bf16 x D | lo bf16 x D ]   (4 bytes/channel, value = hi_f + lo_f,
// representation error ~2^-17 rel). Same memory traffic as fp32, but GEMMs
// load MFMA fragments directly (zero conversion VALU) — round-6 lesson:
// in-GEMM fp32->split conversion was ~85% of GEMM cycles, done 4x redundantly.

__device__ __forceinline__ float u16f(unsigned short u) {
    union { uint32_t u; float f; } c;
    c.u = (uint32_t)u << 16;
    return c.f;
}

// cheap truncating split: f = hi_f + lo_f + err, |err| <= 2^-17 |f|
__device__ __forceinline__ void csplit(float f, short& h, short& l) {
    union { float f; uint32_t u; } x;
    x.f = f;
    h = (short)(x.u >> 16);
    union { uint32_t u; float f; } hf;
    hf.u = x.u & 0xFFFF0000u;
    union { float f; uint32_t u; } y;
    y.f = f - hf.f;  // exact
    l = (short)(y.u >> 16);
}

// ---------------- graph preprocessing (bucketed, atomic-light) ----------------

static __global__ void k_zero(int* __restrict__ gh) {
    int i = threadIdx.x;
    if (i < NBB + 1) gh[i] = 0;
}

static __global__ __launch_bounds__(1024) void k_bhist(const int* __restrict__ dst,
                                                       int* __restrict__ gh) {
    __shared__ int h[NBB + 1];
    int t = threadIdx.x;
    for (int i = t; i < NBB; i += 1024) h[i] = 0;
    __syncthreads();
    int e0 = blockIdx.x * 4096;
#pragma unroll
    for (int j = 0; j < 4; j++) {
        int e = e0 + j * 1024 + t;
        if (e < NE) atomicAdd(&h[dst[e] >> 8], 1);
    }
    __syncthreads();
    for (int i = t; i < NBB; i += 1024)
        if (h[i]) atomicAdd(&gh[i], h[i]);
}

static __global__ void k_bscan(const int* __restrict__ gh, int* __restrict__ gbase,
                               int* __restrict__ gcur) {
    if (threadIdx.x == 0 && blockIdx.x == 0) {
        int s = 0;
        for (int b = 0; b < NBB; b++) {
            gbase[b] = s;
            gcur[b] = s;
            s += gh[b];
        }
        gbase[NBB] = s;  // == NE
    }
}

// staging element packed: (src << 8) | (dst & 255)  -- src < 2^17 fits
static __global__ __launch_bounds__(1024) void k_bscatter(const int* __restrict__ src,
                                                          const int* __restrict__ dst,
                                                          int* __restrict__ gcur,
                                                          int* __restrict__ staging) {
    __shared__ int h[NBB + 1];
    __shared__ int base[NBB + 1];
    int t = threadIdx.x;
    for (int i = t; i < NBB; i += 1024) h[i] = 0;
    __syncthreads();
    int e0 = blockIdx.x * 4096;
    int b[4], l[4], pk[4];
#pragma unroll
    for (int j = 0; j < 4; j++) {
        int e = e0 + j * 1024 + t;
        b[j] = -1;
        if (e < NE) {
            int dv = dst[e];
            pk[j] = (src[e] << 8) | (dv & 255);
            b[j] = dv >> 8;
            l[j] = atomicAdd(&h[b[j]], 1);
        }
    }
    __syncthreads();
    for (int i = t; i < NBB; i += 1024)
        if (h[i]) base[i] = atomicAdd(&gcur[i], h[i]);
    __syncthreads();
#pragma unroll
    for (int j = 0; j < 4; j++)
        if (b[j] >= 0) staging[base[b[j]] + l[j]] = pk[j];
}

static __global__ __launch_bounds__(1024) void k_blocal(const int* __restrict__ staging,
                                                        const int* __restrict__ gbase,
                                                        int* __restrict__ deg,
                                                        float* __restrict__ dinv) {
    __shared__ int cnt[256];
    int b = blockIdx.x;
    int t = threadIdx.x;
    if (t < 256) cnt[t] = 0;
    __syncthreads();
    int end = gbase[b + 1];
    for (int i = gbase[b] + t; i < end; i += 1024)
        atomicAdd(&cnt[staging[i] & 255], 1);
    __syncthreads();
    if (t < 256) {
        int node = (b << 8) + t;
        if (node < NN) {
            int d = cnt[t] + 1;  // +1 self loop
            deg[node] = d;
            dinv[node] = rsqrtf((float)d);
        }
    }
}

static __global__ void k_scan1(const int* __restrict__ deg, int* __restrict__ row_ptr,
                               int* __restrict__ bsums) {
    __shared__ int sd[256];
    int t = threadIdx.x;
    int base = blockIdx.x * 1024;
    int v[4];
    int s = 0;
#pragma unroll
    for (int j = 0; j < 4; j++) {
        int i = base + t * 4 + j;
        int c = (i < NN) ? (deg[i] - 1) : 0;
        v[j] = s;
        s += c;
    }
    sd[t] = s;
    __syncthreads();
    for (int off = 1; off < 256; off <<= 1) {
        int x = (t >= off) ? sd[t - off] : 0;
        __syncthreads();
        sd[t] += x;
        __syncthreads();
    }
    int excl = (t > 0) ? sd[t - 1] : 0;
#pragma unroll
    for (int j = 0; j < 4; j++) {
        int i = base + t * 4 + j;
        if (i < NN) row_ptr[i] = excl + v[j];
    }
    if (t == 255) bsums[blockIdx.x] = sd[255];
}

static __global__ void k_scan2(int* __restrict__ bsums, int nb) {
    if (blockIdx.x == 0 && threadIdx.x == 0) {
        int s = 0;
        for (int i = 0; i < nb; i++) {
            int c = bsums[i];
            bsums[i] = s;
            s += c;
        }
    }
}

static __global__ void k_scan3(int* __restrict__ row_ptr, const int* __restrict__ bsums) {
    int i = blockIdx.x * 256 + threadIdx.x;
    if (i < NN) {
        row_ptr[i] += bsums[i >> 10];
    } else if (i == NN) {
        row_ptr[NN] = NE;
    }
}

static __global__ __launch_bounds__(1024) void k_bfill(const int* __restrict__ staging,
                                                       const int* __restrict__ gbase,
                                                       const int* __restrict__ row_ptr,
                                                       int* __restrict__ csr_src) {
    __shared__ int cnt[256];
    int b = blockIdx.x;
    int t = threadIdx.x;
    if (t < 256) cnt[t] = 0;
    __syncthreads();
    int end = gbase[b + 1];
    for (int i = gbase[b] + t; i < end; i += 1024) {
        int p = staging[i];
        int local = p & 255;
        int r = atomicAdd(&cnt[local], 1);
        csr_src[row_ptr[(b << 8) + local] + r] = p >> 8;
    }
}

// ---------------- weight pre-split into MFMA B-fragment layout ----------------
struct WDesc {
    const float* W;
    short* fh;
    short* fl;
    int din, dout, transb, base, total;  // base/total in short8 groups
};
struct WPrepArgs { WDesc d[6]; };

static __global__ void k_wprep(WPrepArgs args) {
    int tid = blockIdx.x * 256 + threadIdx.x;
#pragma unroll
    for (int i = 0; i < 6; i++) {
        const WDesc& D = args.d[i];
        if (tid >= D.base && tid < D.base + D.total) {
            int local = tid - D.base;
            int lane = local & 63;
            int rest = local >> 6;
            int kst = D.din >> 5;
            int ks = rest % kst;
            int ntile = rest / kst;
            int n = ntile * 16 + (lane & 15);
            int k0 = ks * 32 + (lane >> 4) * 8;
#pragma unroll
            for (int j = 0; j < 8; j++) {
                int k = k0 + j;
                float v = D.transb ? D.W[(size_t)n * D.din + k]
                                   : D.W[(size_t)k * D.dout + n];
                short h, l;
                csplit(v, h, l);
                D.fh[(size_t)local * 8 + j] = h;
                D.fl[(size_t)local * 8 + j] = l;
            }
        }
    }
}

// ---------------- MFMA GEMM: LDS-free, split-plane A, B in registers ----------
// AFP32: A is fp32 (only layer-1 input x) -> cheap in-register split.
// else:  A is split-plane rows -> fragments loaded directly, zero VALU.
// OUTFP32: write fp32 (final output); else write split-plane rows.
template <int DIN, int DOUT, bool AFP32, bool RESID, bool BIAS, bool SCALE, bool OUTFP32>
__global__ __launch_bounds__(256) void k_mgemm(const void* __restrict__ Av,
                                               const short* __restrict__ fh,
                                               const short* __restrict__ fl,
                                               const float* __restrict__ bias,
                                               const float* __restrict__ dinv,
                                               void* __restrict__ Cv) {
    constexpr int KST = DIN / 32;
    constexpr int NTW = DOUT / 64;  // N-tiles per wave; block of 4 waves covers DOUT
    const int t = threadIdx.x;
    const int wave = t >> 6;
    const int lane = t & 63;
    const int r16 = lane & 15;
    const int kq = lane >> 4;

    short8 bh[NTW][KST], bl[NTW][KST];
#pragma unroll
    for (int nt = 0; nt < NTW; nt++) {
        int ntile = wave * NTW + nt;
#pragma unroll
        for (int ks = 0; ks < KST; ks++) {
            size_t o = ((size_t)(ntile * KST + ks) * 64 + lane) * 8;
            bh[nt][ks] = *(const short8*)(fh + o);
            bl[nt][ks] = *(const short8*)(fl + o);
        }
    }

    const float* Af = (const float*)Av;
    const short* As = (const short*)Av;
    float* Cf = (float*)Cv;
    unsigned short* Cs = (unsigned short*)Cv;

    const int m0b = blockIdx.x * 128;
#pragma unroll 1
    for (int mt = 0; mt < 8; mt++) {
        const int m0 = m0b + mt * 16;
        if (m0 >= NN) break;
        const int ra = min(m0 + r16, NN - 1);  // clamp; stores guarded

        short8 ah[KST], al[KST];
        if constexpr (AFP32) {
            const float* Ap = Af + (size_t)ra * DIN + kq * 8;
#pragma unroll
            for (int ks = 0; ks < KST; ks++) {
                float4 f0 = *(const float4*)(Ap + ks * 32);
                float4 f1 = *(const float4*)(Ap + ks * 32 + 4);
                float fe[8] = {f0.x, f0.y, f0.z, f0.w, f1.x, f1.y, f1.z, f1.w};
#pragma unroll
                for (int j = 0; j < 8; j++) {
                    short h, l;
                    csplit(fe[j], h, l);
                    ah[ks][j] = h;
                    al[ks][j] = l;
                }
            }
        } else {
            const short* Ap = As + (size_t)ra * 2 * DIN + kq * 8;
#pragma unroll
            for (int ks = 0; ks < KST; ks++) {
                ah[ks] = *(const short8*)(Ap + ks * 32);
                al[ks] = *(const short8*)(Ap + DIN + ks * 32);
            }
        }

        floatx4 acc[NTW];
#pragma unroll
        for (int nt = 0; nt < NTW; nt++) acc[nt] = (floatx4){0.f, 0.f, 0.f, 0.f};
#pragma unroll
        for (int ks = 0; ks < KST; ks++) {
#pragma unroll
            for (int nt = 0; nt < NTW; nt++) {
                acc[nt] = __builtin_amdgcn_mfma_f32_16x16x32_bf16(ah[ks], bh[nt][ks], acc[nt], 0, 0, 0);
                acc[nt] = __builtin_amdgcn_mfma_f32_16x16x32_bf16(ah[ks], bl[nt][ks], acc[nt], 0, 0, 0);
                acc[nt] = __builtin_amdgcn_mfma_f32_16x16x32_bf16(al[ks], bh[nt][ks], acc[nt], 0, 0, 0);
            }
        }

        // C/D layout: row = kq*4 + r, col = r16 (verified)
#pragma unroll
        for (int nt = 0; nt < NTW; nt++) {
            int col = (wave * NTW + nt) * 16 + r16;
#pragma unroll
            for (int r = 0; r < 4; r++) {
                int row = m0 + kq * 4 + r;
                if (row < NN) {
                    float v = acc[nt][r];
                    if constexpr (RESID) {
                        const unsigned short* Ar =
                            (const unsigned short*)As + (size_t)row * 2 * DIN;
                        float a = u16f(Ar[col]) + u16f(Ar[DIN + col]);
                        v = fmaxf(v + a, 0.f);
                    }
                    if constexpr (BIAS) v = fmaxf(v + bias[col], 0.f);
                    if constexpr (SCALE) v *= dinv[row];
                    if constexpr (OUTFP32) {
                        Cf[(size_t)row * DOUT + col] = v;
                    } else {
                        short h, l;
                        csplit(v, h, l);
                        size_t o = (size_t)row * 2 * DOUT + col;
                        Cs[o] = (unsigned short)h;
                        Cs[o + DOUT] = (unsigned short)l;
                    }
                }
            }
        }
    }
}

// ---------------- GCN aggregation: split-plane rows, 2 nodes/wave --------------
// Input hs PRE-SCALED by dinv (producer epilogue). 32 lanes per node: each lane
// loads UV 32-bit words (hi|lo packed pairs along the row halves) and
// accumulates both planes in fp32. Lanes 0-15 handle the hi half, 16-31 the lo
// half of the row; partials combined by one cross-lane shuffle at the end.
template <int D, bool BIAS_RELU>
__global__ __launch_bounds__(256) void k_agg(const unsigned short* __restrict__ hs,
                                             const float* __restrict__ dinv,
                                             const int* __restrict__ row_ptr,
                                             const int* __restrict__ csr_src,
                                             const float* __restrict__ bias,
                                             unsigned short* __restrict__ out) {
    constexpr int UV = D / 32;   // 32-bit words per lane: 4 (D=128) or 2 (D=64)
    constexpr int CPL = 2 * UV;  // channels covered per writer lane
    const int t = threadIdx.x;
    const int lane64 = t & 63;
    const int node = blockIdx.x * 8 + (t >> 5);
    if (node >= NN) return;
    const int l32 = t & 31;
    const size_t soff = (size_t)l32 * CPL;  // shorts offset into row

    float acc[CPL];
    {
        const uint32_t* p = (const uint32_t*)(hs + (size_t)node * 2 * D + soff);
#pragma unroll
        for (int w = 0; w < UV; w++) {
            uint32_t u = p[w];
            union { uint32_t u; float f; } a, b;
            a.u = u << 16;
            b.u = u & 0xFFFF0000u;
            acc[2 * w] = a.f;
            acc[2 * w + 1] = b.f;
        }
    }

    int e = row_ptr[node];
    const int end = row_ptr[node + 1];

    for (; e + 8 <= end; e += 8) {
        int s[8];
#pragma unroll
        for (int i = 0; i < 8; i++) s[i] = csr_src[e + i];
        uint32_t v[8][UV];
#pragma unroll
        for (int i = 0; i < 8; i++) {
            const uint32_t* p = (const uint32_t*)(hs + (size_t)s[i] * 2 * D + soff);
#pragma unroll
            for (int w = 0; w < UV; w++) v[i][w] = p[w];
        }
#pragma unroll
        for (int i = 0; i < 8; i++)
#pragma unroll
            for (int w = 0; w < UV; w++) {
                union { uint32_t u; float f; } a, b;
                a.u = v[i][w] << 16;
                b.u = v[i][w] & 0xFFFF0000u;
                acc[2 * w] += a.f;
                acc[2 * w + 1] += b.f;
            }
    }
    for (; e + 4 <= end; e += 4) {
        int s[4];
#pragma unroll
        for (int i = 0; i < 4; i++) s[i] = csr_src[e + i];
        uint32_t v[4][UV];
#pragma unroll
        for (int i = 0; i < 4; i++) {
            const uint32_t* p = (const uint32_t*)(hs + (size_t)s[i] * 2 * D + soff);
#pragma unroll
            for (int w = 0; w < UV; w++) v[i][w] = p[w];
        }
#pragma unroll
        for (int i = 0; i < 4; i++)
#pragma unroll
            for (int w = 0; w < UV; w++) {
                union { uint32_t u; float f; } a, b;
                a.u = v[i][w] << 16;
                b.u = v[i][w] & 0xFFFF0000u;
                acc[2 * w] += a.f;
                acc[2 * w + 1] += b.f;
            }
    }
    for (; e < end; e++) {
        const uint32_t* p = (const uint32_t*)(hs + (size_t)csr_src[e] * 2 * D + soff);
#pragma unroll
        for (int w = 0; w < UV; w++) {
            uint32_t u = p[w];
            union { uint32_t u; float f; } a, b;
            a.u = u << 16;
            b.u = u & 0xFFFF0000u;
            acc[2 * w] += a.f;
            acc[2 * w + 1] += b.f;
        }
    }

    // combine hi-lane partial with partner lo-lane partial (channel-aligned)
    float tot[CPL];
    const int srcl = (lane64 & 47) + 16;
#pragma unroll
    for (int j = 0; j < CPL; j++) {
        float o = __shfl(acc[j], srcl, 64);
        tot[j] = acc[j] + o;
    }

    if (l32 < 16) {  // writer lanes own channels [l32*CPL, l32*CPL+CPL)
        const float di = dinv[node];
        const int c0 = l32 * CPL;
        unsigned short hsw[CPL], lsw[CPL];
#pragma unroll
        for (int j = 0; j < CPL; j++) {
            float v = di * tot[j];
            if constexpr (BIAS_RELU) v = fmaxf(v + bias[c0 + j], 0.f);
            short h, l;
            csplit(v, h, l);
            hsw[j] = (unsigned short)h;
            lsw[j] = (unsigned short)l;
        }
        unsigned short* op = out + (size_t)node * 2 * D + c0;
        if constexpr (UV == 4) {
            uintx4 hv, lv;
            hv[0] = hsw[0] | ((uint32_t)hsw[1] << 16);
            hv[1] = hsw[2] | ((uint32_t)hsw[3] << 16);
            hv[2] = hsw[4] | ((uint32_t)hsw[5] << 16);
            hv[3] = hsw[6] | ((uint32_t)hsw[7] << 16);
            lv[0] = lsw[0] | ((uint32_t)lsw[1] << 16);
            lv[1] = lsw[2] | ((uint32_t)lsw[3] << 16);
            lv[2] = lsw[4] | ((uint32_t)lsw[5] << 16);
            lv[3] = lsw[6] | ((uint32_t)lsw[7] << 16);
            __builtin_nontemporal_store(hv, (uintx4*)op);
            __builtin_nontemporal_store(lv, (uintx4*)(op + D));
        } else {
            uintx2 hv, lv;
            hv[0] = hsw[0] | ((uint32_t)hsw[1] << 16);
            hv[1] = hsw[2] | ((uint32_t)hsw[3] << 16);
            lv[0] = lsw[0] | ((uint32_t)lsw[1] << 16);
            lv[1] = lsw[2] | ((uint32_t)lsw[3] << 16);
            __builtin_nontemporal_store(hv, (uintx2*)op);
            __builtin_nontemporal_store(lv, (uintx2*)(op + D));
        }
    }
}

// ---------------- launch ----------------

extern "C" void kernel_launch(void* const* d_in, const int* in_sizes, int n_in,
                              void* d_out, int out_size, void* d_ws, size_t ws_size,
                              hipStream_t stream) {
    const float* x   = (const float*)d_in[0];
    const int*   ei  = (const int*)d_in[1];
    const float* g1w = (const float*)d_in[2];
    const float* g1b = (const float*)d_in[3];
    const float* f2w = (const float*)d_in[4];
    const float* g3w = (const float*)d_in[5];
    const float* g3b = (const float*)d_in[6];
    const float* f4w = (const float*)d_in[7];
    const float* g5w = (const float*)d_in[8];
    const float* g5b = (const float*)d_in[9];
    const float* f6w = (const float*)d_in[10];
    float* out = (float*)d_out;

    const int* src = ei;       // edge_index[0]
    const int* dst = ei + NE;  // edge_index[1]

    char* p = (char*)d_ws;
    auto alloc = [&](size_t bytes) -> void* {
        void* r = (void*)p;
        p += (bytes + 255) & ~(size_t)255;
        return r;
    };
    int*   deg     = (int*)alloc(NN * 4);
    float* dinv    = (float*)alloc(NN * 4);
    int*   row_ptr = (int*)alloc((NN + 1) * 4);
    int*   bsums   = (int*)alloc(512);
    int*   gh      = (int*)alloc((NBB + 1) * 4);
    int*   gbase   = (int*)alloc((NBB + 1) * 4);
    int*   gcur    = (int*)alloc((NBB + 1) * 4);
    int*   csr     = (int*)alloc(NE * 4);
    short* wfh     = (short*)alloc(69632 * 2);
    short* wfl     = (short*)alloc(69632 * 2);
    // bufA/bufB hold split-plane rows: D=128 -> 512 B/row, D=64 -> 256 B/row
    unsigned short* bufA = (unsigned short*)alloc((size_t)NN * 128 * 4);
    unsigned short* bufB = (unsigned short*)alloc((size_t)NN * 128 * 4);
    // packed edge staging (6.4 MB) aliases bufB: fully consumed by
    // k_blocal/k_bfill before agg1 writes bufB (stream-ordered).
    int* staging = (int*)bufB;

    const int gE4 = (NE + 4095) / 4096;      // 391
    const int gS  = (NN + 1023) / 1024;      // 98
    const int gN1 = (NN + 1 + 255) / 256;
    const int gA  = (NN + 7) / 8;            // 12500
    const int gM  = (NN + 127) / 128;        // 782

    // graph preprocessing
    k_zero<<<1, 512, 0, stream>>>(gh);
    k_bhist<<<gE4, 1024, 0, stream>>>(dst, gh);
    k_bscan<<<1, 64, 0, stream>>>(gh, gbase, gcur);
    k_bscatter<<<gE4, 1024, 0, stream>>>(src, dst, gcur, staging);
    k_blocal<<<NBB, 1024, 0, stream>>>(staging, gbase, deg, dinv);
    k_scan1<<<gS, 256, 0, stream>>>(deg, row_ptr, bsums);
    k_scan2<<<1, 64, 0, stream>>>(bsums, gS);
    k_scan3<<<gN1, 256, 0, stream>>>(row_ptr, bsums);
    k_bfill<<<NBB, 1024, 0, stream>>>(staging, gbase, row_ptr, csr);

    // weight fragment prep
    {
        WPrepArgs a;
        int  eoff[6] = {0, 16384, 32768, 40960, 45056, 53248};
        int  base[6] = {0, 2048, 4096, 5120, 5632, 6656};
        int  tot[6]  = {2048, 2048, 1024, 512, 1024, 2048};
        const float* Ws[6] = {g1w, f2w, g3w, f4w, g5w, f6w};
        int din[6]  = {128, 128, 128, 64, 64, 128};
        int dout[6] = {128, 128, 64, 64, 128, 128};
        int trb[6]  = {0, 1, 0, 1, 0, 1};
        for (int i = 0; i < 6; i++) {
            a.d[i] = WDesc{Ws[i], wfh + eoff[i], wfl + eoff[i],
                           din[i], dout[i], trb[i], base[i], tot[i]};
        }
        k_wprep<<<(8704 + 255) / 256, 256, 0, stream>>>(a);
    }

    // layer 1: hs1 = dinv*(x@W1) [split]; z1 = relu(dinv*agg+b1) [split];
    //          z1' = relu(z1 + z1@fc2^T) [split]
    k_mgemm<128, 128, true, false, false, true, false><<<gM, 256, 0, stream>>>(
        x, wfh + 0, wfl + 0, nullptr, dinv, bufA);
    k_agg<128, true><<<gA, 256, 0, stream>>>(bufA, dinv, row_ptr, csr, g1b, bufB);
    k_mgemm<128, 128, false, true, false, false, false><<<gM, 256, 0, stream>>>(
        bufB, wfh + 16384, wfl + 16384, nullptr, nullptr, bufA);

    // layer 2
    k_mgemm<128, 64, false, false, false, true, false><<<gM, 256, 0, stream>>>(
        bufA, wfh + 32768, wfl + 32768, nullptr, dinv, bufB);
    k_agg<64, true><<<gA, 256, 0, stream>>>(bufB, dinv, row_ptr, csr, g3b, bufA);
    k_mgemm<64, 64, false, true, false, true, false><<<gM, 256, 0, stream>>>(
        bufA, wfh + 40960, wfl + 40960, nullptr, dinv, bufB);

    // layer 3 (reordered: aggregate at 64ch, then GEMM)
    k_agg<64, false><<<gA, 256, 0, stream>>>(bufB, dinv, row_ptr, csr, nullptr, bufA);
    k_mgemm<64, 128, false, false, true, false, false><<<gM, 256, 0, stream>>>(
        bufA, wfh + 45056, wfl + 45056, g5b, nullptr, bufB);
    k_mgemm<128, 128, false, true, false, false, true><<<gM, 256, 0, stream>>>(
        bufB, wfh + 53248, wfl + 53248, nullptr, nullptr, out);
}